// Round 8
// baseline (302.096 us; speedup 1.0000x reference)
//
#include <hip/hip_runtime.h>
#include <math.h>

#define KB_   1024                 // z-bins over [-8, 8], Dz = 1/64
#define KPAD  (KB_ + 8)
#define B_IMG 32
#define NB    2048
#define BPI   (NB / B_IMG)         // 64 blocks per image
#define ITERS 16                   // float4 iters per thread (16*256*4*2048 = 32M)

// ws layout (bytes)
#define OFF_HIST  0                         // u32[32][1024] = 131072
#define OFF_IDONE 131072                    // u32[32]
#define OFF_ADONE 131200                    // u32
#define OFF_LOSS  131264                    // f64[32]
#define OFF_FOC   131520                    // f64[32]
#define MEMSET_BYTES 131264                 // hist + counters

// ---- single fused kernel: histogram + last-block scan + last-image final ----
__global__ __launch_bounds__(256)
void k_fused(const float* __restrict__ X, const float* __restrict__ T,
             unsigned* __restrict__ imgHist, unsigned* __restrict__ imgDone,
             unsigned* __restrict__ allDone, double* __restrict__ loss,
             double* __restrict__ fpart, float* __restrict__ out) {
    const int blk = blockIdx.x, tid = threadIdx.x;
    const int img = blk >> 6;                       // blk / BPI
    __shared__ __align__(16) unsigned h[2 * KPAD];  // ~8.2 KB
    __shared__ unsigned sc[2][256];
    __shared__ double sN[4], sFo[4];
    __shared__ unsigned sFlag;

    for (int i = tid; i < 2 * KPAD; i += 256) h[i] = 0u;
    __syncthreads();

    unsigned* hp = h + (tid & 1) * KPAD;
    const size_t base4 = (size_t)blk * (size_t)ITERS * 256;
    const float4* Xp = (const float4*)X + base4 + tid;
    const float4* Tp = (const float4*)T + base4 + tid;

    auto process = [&](float4 xv, float4 tv) {
#pragma unroll
        for (int j = 0; j < 4; ++j) {
            float x = (&xv.x)[j];
            float t = (&tv.x)[j];
            float s    = __builtin_fmaf(2.f, t, -1.f);            // +1 / -1
            float z    = x * s;                                    // signed logit
            float binf = __builtin_fmaf(z, 64.f, 512.f);
            binf = fminf(fmaxf(binf, 0.f), 1023.f);
            int bin = (int)binf;
            unsigned incr = (unsigned)__builtin_fmaf(t, 65536.f, 1.f); // (t<<16)|1
            atomicAdd(&hp[bin], incr);
        }
    };

    float4 bx[4], bt[4];
#pragma unroll
    for (int r = 0; r < 4; ++r) { bx[r] = Xp[r * 256]; bt[r] = Tp[r * 256]; }
#pragma unroll
    for (int r = 0; r < ITERS; ++r) {
        float4 xv = bx[r & 3], tv = bt[r & 3];
        if (r + 4 < ITERS) {
            bx[r & 3] = Xp[(r + 4) * 256];
            bt[r & 3] = Tp[(r + 4) * 256];
        }
        process(xv, tv);
    }
    __syncthreads();

    // flush block hist into per-image global hist (integer atomics: deterministic)
    unsigned* ih = imgHist + (size_t)img * KB_;
    for (int i = tid; i < KB_; i += 256) {
        unsigned v = h[i] + h[KPAD + i];
        if (v) atomicAdd(&ih[i], v);
    }
    __threadfence();
    __syncthreads();
    if (tid == 0) sFlag = (atomicAdd(&imgDone[img], 1u) == BPI - 1) ? 1u : 0u;
    __syncthreads();
    if (!sFlag) return;

    // ---- last block of this image: suffix scan + analytic dot ----
    unsigned pk[4], ck[4];
#pragma unroll
    for (int i = 0; i < 4; ++i) {
        unsigned v = atomicAdd(&ih[tid * 4 + i], 0u);   // coherent read
        pk[i] = v >> 16; ck[i] = v & 0xffffu;
    }
    unsigned tsum = pk[0] + pk[1] + pk[2] + pk[3];

    sc[0][tid] = tsum;
    __syncthreads();
    int pi = 0;
    for (int off = 1; off < 256; off <<= 1) {
        unsigned val = sc[pi][tid];
        if (tid + off < 256) val += sc[pi][tid + off];
        sc[pi ^ 1][tid] = val;
        __syncthreads();
        pi ^= 1;
    }
    unsigned sufT  = sc[pi][tid] - tsum;   // positives in threads > tid
    unsigned denom = sc[pi][0];            // total positives in image

    double nsum = 0.0, fsum = 0.0;
    unsigned a2 = 0;
#pragma unroll
    for (int i = 3; i >= 0; --i) {
        int b = tid * 4 + i;
        double zc = ((double)b + 0.5 - 512.0) * (1.0 / 64.0);
        double az = fabs(zc);
        double e  = exp(-az);
        double am = (1.0 - e) / (1.0 + e);                         // |margin|
        double om = (zc >= 0.0) ? e / (1.0 + e) : 1.0 / (1.0 + e); // sigmoid(-z)
        double bce = ((zc < 0.0) ? -zc : 0.0) + log1p(e);          // softplus(-z)
        double fk = om * om * bce;
        double Sab = (double)(sufT + a2);
        double c = (double)ck[i], p = (double)pk[i];
        nsum += am * (c * Sab + 0.5 * p * (c + 1.0));
        fsum += fk * c;
        a2 += pk[i];
    }
    for (int o = 32; o > 0; o >>= 1) {
        nsum += __shfl_down(nsum, o, 64);
        fsum += __shfl_down(fsum, o, 64);
    }
    if ((tid & 63) == 0) { sN[tid >> 6] = nsum; sFo[tid >> 6] = fsum; }
    __syncthreads();
    if (tid == 0) {
        double num = sN[0] + sN[1] + sN[2] + sN[3];
        loss[img]  = (denom == 0u) ? 0.0 : num / fmax((double)denom, 1.0);
        fpart[img] = sFo[0] + sFo[1] + sFo[2] + sFo[3];
        __threadfence();
        sFlag = (atomicAdd(allDone, 1u) == B_IMG - 1) ? 2u : 0u;
    }
    __syncthreads();
    if (sFlag != 2u) return;

    // ---- last image finisher: combine 32 images, write output ----
    double l = 0.0, f = 0.0;
    if (tid < B_IMG) {
        l = atomicAdd(&loss[tid], 0.0);     // coherent f64 reads
        f = atomicAdd(&fpart[tid], 0.0);
    }
    if (tid < 64) {
        for (int o = 32; o > 0; o >>= 1) {
            l += __shfl_down(l, o, 64);
            f += __shfl_down(f, o, 64);
        }
        if (tid == 0) {
            double lmean = l / (double)B_IMG;
            double fmean = f / 33554432.0;  // 32 * 2^20 elements
            out[0] = (float)(fabs(0.5 * fmean) + fabs(0.5 * lmean));
        }
    }
}

extern "C" void kernel_launch(void* const* d_in, const int* in_sizes, int n_in,
                              void* d_out, int out_size, void* d_ws, size_t ws_size,
                              hipStream_t stream) {
    const float* X = (const float*)d_in[0];
    const float* T = (const float*)d_in[1];
    unsigned char* ws = (unsigned char*)d_ws;

    unsigned* imgHist = (unsigned*)(ws + OFF_HIST);
    unsigned* imgDone = (unsigned*)(ws + OFF_IDONE);
    unsigned* allDone = (unsigned*)(ws + OFF_ADONE);
    double*   loss    = (double*)(ws + OFF_LOSS);
    double*   fpart   = (double*)(ws + OFF_FOC);

    hipMemsetAsync(ws, 0, MEMSET_BYTES, stream);
    k_fused<<<NB, 256, 0, stream>>>(X, T, imgHist, imgDone, allDone,
                                    loss, fpart, (float*)d_out);
}

// Round 9
// 51.143 us; speedup vs baseline: 5.9069x; 5.9069x over previous
//
#include <hip/hip_runtime.h>
#include <math.h>

#define KB_   1024                 // z-bins over [-8, 8], Dz = 1/64
#define KPAD  (KB_ + 8)
#define B_IMG 32

// ---------------- pass 1: z-binned packed count histogram ------------------
// Per element: z = t? x : -x ; bin = clamp(z*64+512) ; h[bin] += (t<<16)|1.
template <int ITERS>
__global__ __launch_bounds__(256)
void k_pass1(const float* __restrict__ X, const float* __restrict__ T,
             unsigned* __restrict__ ghist, float* __restrict__ out) {
    const int blk = blockIdx.x, tid = threadIdx.x;
    if (blk == 0 && tid == 0) out[0] = 0.f;        // zero output for k_scan's atomics
    __shared__ __align__(16) unsigned h[2 * KPAD]; // ~8.2 KB
    for (int i = tid; i < 2 * KPAD; i += 256) h[i] = 0u;
    __syncthreads();

    unsigned* hp = h + (tid & 1) * KPAD;
    const size_t base4 = (size_t)blk * (size_t)ITERS * 256;
    const float4* Xp = (const float4*)X + base4 + tid;
    const float4* Tp = (const float4*)T + base4 + tid;

    auto process = [&](float4 xv, float4 tv) {
#pragma unroll
        for (int j = 0; j < 4; ++j) {
            float x = (&xv.x)[j];
            float t = (&tv.x)[j];
            float s    = __builtin_fmaf(2.f, t, -1.f);            // +1 / -1
            float z    = x * s;                                    // signed logit
            float binf = __builtin_fmaf(z, 64.f, 512.f);
            binf = fminf(fmaxf(binf, 0.f), 1023.f);
            int bin = (int)binf;
            unsigned incr = (unsigned)__builtin_fmaf(t, 65536.f, 1.f); // (t<<16)|1
            atomicAdd(&hp[bin], incr);
        }
    };

    float4 bx[4], bt[4];
#pragma unroll
    for (int r = 0; r < 4; ++r) { bx[r] = Xp[r * 256]; bt[r] = Tp[r * 256]; }
#pragma unroll
    for (int r = 0; r < ITERS; ++r) {
        float4 xv = bx[r & 3], tv = bt[r & 3];
        if (r + 4 < ITERS) {
            bx[r & 3] = Xp[(r + 4) * 256];
            bt[r & 3] = Tp[(r + 4) * 256];
        }
        process(xv, tv);
    }
    __syncthreads();

    unsigned* g = ghist + (size_t)blk * KB_;
    for (int i = tid; i < KB_; i += 256) g[i] = h[i] + h[KPAD + i];
}

// ---------------- per-image: accumulate + suffix scan + analytic dot -------
// Output contribution added directly to out[0] (both loss terms are >= 0,
// so the reference's abs() is a no-op and the final combine is a plain sum).
__global__ __launch_bounds__(256)
void k_scan(const unsigned* __restrict__ ghist, float* __restrict__ out, int bpi) {
    const int img = blockIdx.x, tid = threadIdx.x;
    const unsigned* g = ghist + (size_t)img * (size_t)bpi * KB_;

    uint4 acc = make_uint4(0u, 0u, 0u, 0u);
#pragma unroll 8
    for (int j = 0; j < bpi; ++j) {
        uint4 v = *(const uint4*)&g[(size_t)j * KB_ + tid * 4];
        acc.x += v.x; acc.y += v.y; acc.z += v.z; acc.w += v.w;
    }
    unsigned pk[4], ck[4];
    pk[0] = acc.x >> 16; ck[0] = acc.x & 0xffffu;
    pk[1] = acc.y >> 16; ck[1] = acc.y & 0xffffu;
    pk[2] = acc.z >> 16; ck[2] = acc.z & 0xffffu;
    pk[3] = acc.w >> 16; ck[3] = acc.w & 0xffffu;

    unsigned tsum = pk[0] + pk[1] + pk[2] + pk[3];

    __shared__ unsigned sc[2][256];
    sc[0][tid] = tsum;
    __syncthreads();
    int pi = 0;
    for (int off = 1; off < 256; off <<= 1) {
        unsigned val = sc[pi][tid];
        if (tid + off < 256) val += sc[pi][tid + off];
        sc[pi ^ 1][tid] = val;
        __syncthreads();
        pi ^= 1;
    }
    unsigned sufT  = sc[pi][tid] - tsum;   // positives in threads > tid
    unsigned denom = sc[pi][0];            // total positives in image

    double nsum = 0.0, fsum = 0.0;
    unsigned a2 = 0;
#pragma unroll
    for (int i = 3; i >= 0; --i) {
        int b = tid * 4 + i;
        double zc = ((double)b + 0.5 - 512.0) * (1.0 / 64.0);
        double az = fabs(zc);
        double e  = exp(-az);
        double am = (1.0 - e) / (1.0 + e);                         // |margin|
        double om = (zc >= 0.0) ? e / (1.0 + e) : 1.0 / (1.0 + e); // sigmoid(-z)
        double bce = ((zc < 0.0) ? -zc : 0.0) + log1p(e);          // softplus(-z)
        double fk = om * om * bce;
        double Sab = (double)(sufT + a2);
        double c = (double)ck[i], p = (double)pk[i];
        nsum += am * (c * Sab + 0.5 * p * (c + 1.0));
        fsum += fk * c;
        a2 += pk[i];
    }

    for (int o = 32; o > 0; o >>= 1) {
        nsum += __shfl_down(nsum, o, 64);
        fsum += __shfl_down(fsum, o, 64);
    }
    __shared__ double sN[4], sFo[4];
    if ((tid & 63) == 0) { sN[tid >> 6] = nsum; sFo[tid >> 6] = fsum; }
    __syncthreads();
    if (tid == 0) {
        double num  = sN[0] + sN[1] + sN[2] + sN[3];
        double lv   = (denom == 0u) ? 0.0 : num / fmax((double)denom, 1.0);
        double foc  = sFo[0] + sFo[1] + sFo[2] + sFo[3];
        float contrib = (float)(0.5 * lv / (double)B_IMG
                              + 0.5 * foc / 33554432.0);   // 32 * 2^20
        atomicAdd(out, contrib);
    }
}

extern "C" void kernel_launch(void* const* d_in, const int* in_sizes, int n_in,
                              void* d_out, int out_size, void* d_ws, size_t ws_size,
                              hipStream_t stream) {
    const float* X = (const float*)d_in[0];
    const float* T = (const float*)d_in[1];

    int NB = 1024;                                 // 4 blocks/CU, ~8 KB LDS each
    for (;;) {
        size_t need = (size_t)NB * KB_ * 4 + 1024;
        if (need <= ws_size || NB <= 256) break;
        NB >>= 1;
    }
    const int bpi = NB / B_IMG;

    unsigned* ghist = (unsigned*)d_ws;
    float*    out   = (float*)d_out;

    switch (NB) {
        case 1024: k_pass1<32> <<<1024, 256, 0, stream>>>(X, T, ghist, out); break;
        case 512:  k_pass1<64> <<<512,  256, 0, stream>>>(X, T, ghist, out); break;
        default:   k_pass1<128><<<256,  256, 0, stream>>>(X, T, ghist, out); break;
    }
    k_scan<<<B_IMG, 256, 0, stream>>>(ghist, out, bpi);
}

// Round 10
// 50.407 us; speedup vs baseline: 5.9931x; 1.0146x over previous
//
#include <hip/hip_runtime.h>
#include <math.h>

#define KB_   1024                 // z-bins over [-8, 8], Dz = 1/64
#define KPAD  (KB_ + 8)
#define B_IMG 32

// ---------------- pass 1: z-binned packed count histogram ------------------
// Per element: z = t? x : -x ; bin = clamp(z*64+512) ; h[bin] += (t<<16)|1.
template <int ITERS>
__global__ __launch_bounds__(256)
void k_pass1(const float* __restrict__ X, const float* __restrict__ T,
             unsigned* __restrict__ ghist, float* __restrict__ out) {
    const int blk = blockIdx.x, tid = threadIdx.x;
    if (blk == 0 && tid == 0) out[0] = 0.f;        // zero output for k_scan's atomics
    __shared__ __align__(16) unsigned h[2 * KPAD]; // ~8.2 KB
    for (int i = tid; i < 2 * KPAD; i += 256) h[i] = 0u;
    __syncthreads();

    unsigned* hp = h + (tid & 1) * KPAD;
    const size_t base4 = (size_t)blk * (size_t)ITERS * 256;
    const float4* Xp = (const float4*)X + base4 + tid;
    const float4* Tp = (const float4*)T + base4 + tid;

    auto process = [&](float4 xv, float4 tv) {
#pragma unroll
        for (int j = 0; j < 4; ++j) {
            float x = (&xv.x)[j];
            float t = (&tv.x)[j];
            float s    = __builtin_fmaf(2.f, t, -1.f);            // +1 / -1
            float z    = x * s;                                    // signed logit
            float binf = __builtin_fmaf(z, 64.f, 512.f);
            binf = fminf(fmaxf(binf, 0.f), 1023.f);
            int bin = (int)binf;
            unsigned incr = (unsigned)__builtin_fmaf(t, 65536.f, 1.f); // (t<<16)|1
            atomicAdd(&hp[bin], incr);
        }
    };

    float4 bx[4], bt[4];
#pragma unroll
    for (int r = 0; r < 4; ++r) { bx[r] = Xp[r * 256]; bt[r] = Tp[r * 256]; }
#pragma unroll
    for (int r = 0; r < ITERS; ++r) {
        float4 xv = bx[r & 3], tv = bt[r & 3];
        if (r + 4 < ITERS) {
            bx[r & 3] = Xp[(r + 4) * 256];
            bt[r & 3] = Tp[(r + 4) * 256];
        }
        process(xv, tv);
    }
    __syncthreads();

    unsigned* g = ghist + (size_t)blk * KB_;
    for (int i = tid; i < KB_; i += 256) g[i] = h[i] + h[KPAD + i];
}

// ---------------- per-image: accumulate + suffix scan + analytic dot -------
// Output contribution added directly to out[0] (both loss terms are >= 0,
// so the reference's abs() is a no-op and the final combine is a plain sum).
template <int BPI>
__global__ __launch_bounds__(256)
void k_scan(const unsigned* __restrict__ ghist, float* __restrict__ out) {
    const int img = blockIdx.x, tid = threadIdx.x;
    const unsigned* g = ghist + (size_t)img * (size_t)BPI * KB_;

    uint4 acc = make_uint4(0u, 0u, 0u, 0u);
#pragma unroll
    for (int j = 0; j < BPI; ++j) {
        uint4 v = *(const uint4*)&g[(size_t)j * KB_ + tid * 4];
        acc.x += v.x; acc.y += v.y; acc.z += v.z; acc.w += v.w;
    }
    unsigned pk[4], ck[4];
    pk[0] = acc.x >> 16; ck[0] = acc.x & 0xffffu;
    pk[1] = acc.y >> 16; ck[1] = acc.y & 0xffffu;
    pk[2] = acc.z >> 16; ck[2] = acc.z & 0xffffu;
    pk[3] = acc.w >> 16; ck[3] = acc.w & 0xffffu;

    unsigned tsum = pk[0] + pk[1] + pk[2] + pk[3];

    __shared__ unsigned sc[2][256];
    sc[0][tid] = tsum;
    __syncthreads();
    int pi = 0;
    for (int off = 1; off < 256; off <<= 1) {
        unsigned val = sc[pi][tid];
        if (tid + off < 256) val += sc[pi][tid + off];
        sc[pi ^ 1][tid] = val;
        __syncthreads();
        pi ^= 1;
    }
    unsigned sufT  = sc[pi][tid] - tsum;   // positives in threads > tid
    unsigned denom = sc[pi][0];            // total positives in image

    double nsum = 0.0, fsum = 0.0;
    unsigned a2 = 0;
#pragma unroll
    for (int i = 3; i >= 0; --i) {
        int b = tid * 4 + i;
        double zc = ((double)b + 0.5 - 512.0) * (1.0 / 64.0);
        double az = fabs(zc);
        double e  = exp(-az);
        double am = (1.0 - e) / (1.0 + e);                         // |margin|
        double om = (zc >= 0.0) ? e / (1.0 + e) : 1.0 / (1.0 + e); // sigmoid(-z)
        double bce = ((zc < 0.0) ? -zc : 0.0) + log1p(e);          // softplus(-z)
        double fk = om * om * bce;
        double Sab = (double)(sufT + a2);
        double c = (double)ck[i], p = (double)pk[i];
        nsum += am * (c * Sab + 0.5 * p * (c + 1.0));
        fsum += fk * c;
        a2 += pk[i];
    }

    for (int o = 32; o > 0; o >>= 1) {
        nsum += __shfl_down(nsum, o, 64);
        fsum += __shfl_down(fsum, o, 64);
    }
    __shared__ double sN[4], sFo[4];
    if ((tid & 63) == 0) { sN[tid >> 6] = nsum; sFo[tid >> 6] = fsum; }
    __syncthreads();
    if (tid == 0) {
        double num  = sN[0] + sN[1] + sN[2] + sN[3];
        double lv   = (denom == 0u) ? 0.0 : num / fmax((double)denom, 1.0);
        double foc  = sFo[0] + sFo[1] + sFo[2] + sFo[3];
        float contrib = (float)(0.5 * lv / (double)B_IMG
                              + 0.5 * foc / 33554432.0);   // 32 * 2^20
        atomicAdd(out, contrib);
    }
}

extern "C" void kernel_launch(void* const* d_in, const int* in_sizes, int n_in,
                              void* d_out, int out_size, void* d_ws, size_t ws_size,
                              hipStream_t stream) {
    const float* X = (const float*)d_in[0];
    const float* T = (const float*)d_in[1];

    int NB = 512;                                  // 2 blocks/CU, ~8 KB LDS each
    for (;;) {
        size_t need = (size_t)NB * KB_ * 4 + 1024;
        if (need <= ws_size || NB <= 256) break;
        NB >>= 1;
    }

    unsigned* ghist = (unsigned*)d_ws;
    float*    out   = (float*)d_out;

    if (NB >= 512) {
        k_pass1<64> <<<512, 256, 0, stream>>>(X, T, ghist, out);
        k_scan<16>  <<<B_IMG, 256, 0, stream>>>(ghist, out);
    } else {
        k_pass1<128><<<256, 256, 0, stream>>>(X, T, ghist, out);
        k_scan<8>   <<<B_IMG, 256, 0, stream>>>(ghist, out);
    }
}